// Round 3
// baseline (809.620 us; speedup 1.0000x reference)
//
#include <hip/hip_runtime.h>

#define N_ROWS 200000
#define P 576
#define P4 144   // P / 4 float4 column-groups
#define GRID1 1024

typedef float floatx4 __attribute__((ext_vector_type(4)));

// ws layout: S1[P] floats, S2[P] floats, counter (1 uint) — zeroed before launch

__global__ __launch_bounds__(576) void fused_kernel(const floatx4* __restrict__ X4,
                                                    const float* __restrict__ mu,
                                                    const float* __restrict__ W,
                                                    float* __restrict__ S1,
                                                    float* __restrict__ S2,
                                                    unsigned int* __restrict__ counter,
                                                    float* __restrict__ out) {
    const int x = threadIdx.x;   // [0,144): float4 column group
    const int y = threadIdx.y;   // [0,4):   row offset within block stripe
    const int tid = y * P4 + x;

    floatx4 s1 = {0.f, 0.f, 0.f, 0.f};
    floatx4 s2 = {0.f, 0.f, 0.f, 0.f};

    for (int r = blockIdx.x * 4 + y; r < N_ROWS; r += GRID1 * 4) {
        floatx4 v = __builtin_nontemporal_load(&X4[(size_t)r * P4 + x]);
        s1 += v;
        s2 += v * v;
    }

    __shared__ floatx4 sh1[4][P4];
    __shared__ floatx4 sh2[4][P4];
    sh1[y][x] = s1;
    sh2[y][x] = s2;
    __syncthreads();

    if (y == 0) {
        #pragma unroll
        for (int i = 1; i < 4; ++i) {
            s1 += sh1[i][x];
            s2 += sh2[i][x];
        }
        atomicAdd(&S1[4 * x + 0], s1.x);
        atomicAdd(&S1[4 * x + 1], s1.y);
        atomicAdd(&S1[4 * x + 2], s1.z);
        atomicAdd(&S1[4 * x + 3], s1.w);
        atomicAdd(&S2[4 * x + 0], s2.x);
        atomicAdd(&S2[4 * x + 1], s2.y);
        atomicAdd(&S2[4 * x + 2], s2.z);
        atomicAdd(&S2[4 * x + 3], s2.w);
    }

    // ---- last-block-done: the final block performs the projection ----
    __threadfence();  // make our atomicAdds visible device-wide before ticketing
    __shared__ unsigned int ticket;
    __syncthreads();
    if (tid == 0) ticket = atomicAdd(counter, 1u);
    __syncthreads();
    if (ticket != GRID1 - 1) return;

    __threadfence();  // acquire: all other blocks' adds are visible

    const float invN = 1.0f / (float)N_ROWS;
    float acc0 = 0.f, acc1 = 0.f, acc2 = 0.f, acc3 = 0.f;

    if (tid < 256) {
        for (int p = tid; p < P; p += 256) {
            // atomic read-with-add(0) guarantees device-scope coherent view
            float sv1 = atomicAdd(&S1[p], 0.0f);
            float sv2 = atomicAdd(&S2[p], 0.0f);
            float m    = sv1 * invN;
            float mom2 = sv2 * invN - m * m;
            int j = 3 * p;
            float c0 = m    - mu[j];
            float c1 = 0.f  - mu[j + 1];
            float c2 = mom2 - mu[j + 2];
            const float* w0 = &W[(size_t)j * 4];
            acc0 += c0 * w0[0] + c1 * w0[4] + c2 * w0[8];
            acc1 += c0 * w0[1] + c1 * w0[5] + c2 * w0[9];
            acc2 += c0 * w0[2] + c1 * w0[6] + c2 * w0[10];
            acc3 += c0 * w0[3] + c1 * w0[7] + c2 * w0[11];
        }
        #pragma unroll
        for (int off = 32; off > 0; off >>= 1) {
            acc0 += __shfl_down(acc0, off);
            acc1 += __shfl_down(acc1, off);
            acc2 += __shfl_down(acc2, off);
            acc3 += __shfl_down(acc3, off);
        }
    }

    __shared__ float sacc[4][4];  // [wave][k]
    const int wave = tid >> 6;
    const int lane = tid & 63;
    if (tid < 256 && lane == 0) {
        sacc[wave][0] = acc0;
        sacc[wave][1] = acc1;
        sacc[wave][2] = acc2;
        sacc[wave][3] = acc3;
    }
    __syncthreads();
    if (tid < 4) {
        out[tid] = sacc[0][tid] + sacc[1][tid] + sacc[2][tid] + sacc[3][tid];
    }
}

extern "C" void kernel_launch(void* const* d_in, const int* in_sizes, int n_in,
                              void* d_out, int out_size, void* d_ws, size_t ws_size,
                              hipStream_t stream) {
    const float* X  = (const float*)d_in[0];   // (200000, 576) fp32
    const float* mu = (const float*)d_in[1];   // (1728,)
    const float* W  = (const float*)d_in[2];   // (1728, 4)
    float* out = (float*)d_out;                // (4,)

    float* S1 = (float*)d_ws;
    float* S2 = S1 + P;
    unsigned int* counter = (unsigned int*)(S2 + P);

    (void)hipMemsetAsync(d_ws, 0, (2 * P + 1) * sizeof(float), stream);

    dim3 block(P4, 4);  // 576 threads = 9 waves
    fused_kernel<<<GRID1, block, 0, stream>>>((const floatx4*)X, mu, W,
                                              S1, S2, counter, out);
}